// Round 1
// baseline (353.753 us; speedup 1.0000x reference)
//
#include <hip/hip_runtime.h>

#define BATCH 4
#define CCH 128
#define NSP 4096
#define NGRP 8
#define GROUP_ELEMS 65536   // 16 ch * 4096
#define ATT_SCALE 0.08838834764831845f
#define EPS_GN 1e-5f

typedef short s8b __attribute__((ext_vector_type(8)));
typedef float f32x4 __attribute__((ext_vector_type(4)));

static __device__ __forceinline__ short f2bf(float f) {
  union { float f; unsigned u; } v; v.f = f;
  unsigned r = (v.u + 0x7FFFu + ((v.u >> 16) & 1u)) >> 16;
  return (short)r;
}

static __device__ __forceinline__ f32x4 mfma16(s8b a, s8b b, f32x4 c) {
  return __builtin_amdgcn_mfma_f32_16x16x32_bf16(a, b, c, 0, 0, 0);
}

// ---------------- GroupNorm pass 1: per-(b,g) sum / sumsq ----------------
__global__ void gn_stats(const float* __restrict__ x, float* __restrict__ stats) {
  int bx = blockIdx.x;            // 256 = bg(32) * chunk(8)
  int ch = bx & 7, bg = bx >> 3;
  const float* base = x + (size_t)bg * GROUP_ELEMS + (size_t)ch * 8192;
  int t = threadIdx.x;
  float s = 0.f, ss = 0.f;
  #pragma unroll
  for (int i = 0; i < 8; ++i) {
    float4 v = *(const float4*)(base + i * 1024 + t * 4);
    s  += v.x + v.y + v.z + v.w;
    ss += v.x * v.x + v.y * v.y + v.z * v.z + v.w * v.w;
  }
  #pragma unroll
  for (int off = 1; off < 64; off <<= 1) {
    s  += __shfl_xor(s, off);
    ss += __shfl_xor(ss, off);
  }
  __shared__ float red[8];
  int w = t >> 6;
  if ((t & 63) == 0) { red[w * 2] = s; red[w * 2 + 1] = ss; }
  __syncthreads();
  if (t == 0) {
    atomicAdd(&stats[bg * 2],     red[0] + red[2] + red[4] + red[6]);
    atomicAdd(&stats[bg * 2 + 1], red[1] + red[3] + red[5] + red[7]);
  }
}

// ---------------- GroupNorm pass 2: normalize, write xn as (b,n,c) bf16 ----------------
__global__ void gn_apply(const float* __restrict__ x, const float* __restrict__ gw,
                         const float* __restrict__ gb, const float* __restrict__ stats,
                         short* __restrict__ xn) {
  int bx = blockIdx.x;            // 256 = b(4) g(8) ns(8)
  int ns = bx & 7, g = (bx >> 3) & 7, b = bx >> 6;
  int bg = b * NGRP + g;
  float mean = stats[bg * 2] * (1.f / GROUP_ELEMS);
  float var  = stats[bg * 2 + 1] * (1.f / GROUP_ELEMS) - mean * mean;
  float inv  = rsqrtf(var + EPS_GN);
  int t = threadIdx.x;
  int cl = t & 15, n4 = t >> 4;
  int c = g * 16 + cl;
  float ga = gw[c] * inv;
  float be = gb[c] - mean * ga;
  const float* xr = x + (size_t)(b * CCH + c) * NSP;
  short* xo = xn + (size_t)b * NSP * CCH + c;
  #pragma unroll
  for (int i = 0; i < 8; ++i) {
    int n = ns * 512 + i * 64 + n4 * 4;
    float4 v = *(const float4*)(xr + n);
    xo[(size_t)(n + 0) * CCH] = f2bf(v.x * ga + be);
    xo[(size_t)(n + 1) * CCH] = f2bf(v.y * ga + be);
    xo[(size_t)(n + 2) * CCH] = f2bf(v.z * ga + be);
    xo[(size_t)(n + 3) * CCH] = f2bf(v.w * ga + be);
  }
}

// ---------------- QKV (q,k part): D[n][o], writes q,k as (b,n,c) bf16 ----------------
__global__ void qk_gemm(const short* __restrict__ xn, const float* __restrict__ Wqkv,
                        const float* __restrict__ bias, short* __restrict__ q,
                        short* __restrict__ k) {
  int bx = blockIdx.x;            // 1024 = b(4) nt(64) ot(4)
  int ot = bx & 3, nt = (bx >> 2) & 63, b = bx >> 8;
  __shared__ short Xl[64][136];
  __shared__ short Wl[64][136];
  int t = threadIdx.x;
  for (int idx = t; idx < 64 * 16; idx += 256) {
    int row = idx >> 4, c8 = idx & 15;
    *(s8b*)&Xl[row][c8 * 8] =
        *(const s8b*)(xn + ((size_t)(b * NSP + nt * 64 + row)) * CCH + c8 * 8);
  }
  for (int idx = t; idx < 64 * 16; idx += 256) {
    int row = idx >> 4, c8 = idx & 15;
    const float* src = Wqkv + (size_t)(ot * 64 + row) * CCH + c8 * 8;
    s8b wv;
    #pragma unroll
    for (int j = 0; j < 8; ++j) wv[j] = f2bf(src[j]);
    *(s8b*)&Wl[row][c8 * 8] = wv;
  }
  __syncthreads();
  int lane = t & 63, w = t >> 6, l15 = lane & 15, quad = lane >> 4;
  s8b a[4];
  #pragma unroll
  for (int kc = 0; kc < 4; ++kc) a[kc] = *(const s8b*)&Xl[w * 16 + l15][kc * 32 + quad * 8];
  #pragma unroll
  for (int o4 = 0; o4 < 4; ++o4) {
    f32x4 acc = {0.f, 0.f, 0.f, 0.f};
    #pragma unroll
    for (int kc = 0; kc < 4; ++kc) {
      s8b bw = *(const s8b*)&Wl[o4 * 16 + l15][kc * 32 + quad * 8];
      acc = mfma16(a[kc], bw, acc);
    }
    int obase = ot * 64 + o4 * 16;
    short* dst = (obase < 128) ? q : k;
    int oc = obase - ((obase < 128) ? 0 : 128) + l15;
    float bs = bias[obase + l15];
    #pragma unroll
    for (int r = 0; r < 4; ++r) {
      int n = nt * 64 + w * 16 + quad * 4 + r;
      dst[((size_t)(b * NSP + n)) * CCH + oc] = f2bf(acc[r] + bs);
    }
  }
}

// ---------------- QKV (v part): D[o][n], writes v transposed (b,c,n) bf16 ----------------
__global__ void v_gemm(const short* __restrict__ xn, const float* __restrict__ Wqkv,
                       const float* __restrict__ bias, short* __restrict__ vt) {
  int bx = blockIdx.x;            // 256 = b(4) nt(32) ot(2)
  int ot = bx & 1, nt = (bx >> 1) & 31, b = bx >> 6;
  __shared__ short Xl[128][136];
  __shared__ short Wl[64][136];
  int t = threadIdx.x;
  for (int idx = t; idx < 128 * 16; idx += 256) {
    int row = idx >> 4, c8 = idx & 15;
    *(s8b*)&Xl[row][c8 * 8] =
        *(const s8b*)(xn + ((size_t)(b * NSP + nt * 128 + row)) * CCH + c8 * 8);
  }
  for (int idx = t; idx < 64 * 16; idx += 256) {
    int row = idx >> 4, c8 = idx & 15;
    const float* src = Wqkv + (size_t)(256 + ot * 64 + row) * CCH + c8 * 8;
    s8b wv;
    #pragma unroll
    for (int j = 0; j < 8; ++j) wv[j] = f2bf(src[j]);
    *(s8b*)&Wl[row][c8 * 8] = wv;
  }
  __syncthreads();
  int lane = t & 63, w = t >> 6, l15 = lane & 15, quad = lane >> 4;
  s8b a[4];
  #pragma unroll
  for (int kc = 0; kc < 4; ++kc) a[kc] = *(const s8b*)&Wl[w * 16 + l15][kc * 32 + quad * 8];
  float bs[4];
  #pragma unroll
  for (int r = 0; r < 4; ++r) bs[r] = bias[256 + ot * 64 + w * 16 + quad * 4 + r];
  #pragma unroll
  for (int ntile = 0; ntile < 8; ++ntile) {
    f32x4 acc = {0.f, 0.f, 0.f, 0.f};
    #pragma unroll
    for (int kc = 0; kc < 4; ++kc) {
      s8b bx2 = *(const s8b*)&Xl[ntile * 16 + l15][kc * 32 + quad * 8];
      acc = mfma16(a[kc], bx2, acc);
    }
    #pragma unroll
    for (int r = 0; r < 4; ++r) {
      int og = ot * 64 + w * 16 + quad * 4 + r;       // v channel
      int n = nt * 128 + ntile * 16 + l15;
      vt[((size_t)(b * CCH + og)) * NSP + n] = f2bf(acc[r] + bs[r]);
    }
  }
}

// ---------------- Flash attention: Q-tile 64 rows/block, K/V tiles 64 via LDS ----------------
__global__ __launch_bounds__(256) void flash(const short* __restrict__ q,
                                             const short* __restrict__ k,
                                             const short* __restrict__ vt,
                                             short* __restrict__ ao) {
  int bx = blockIdx.x;            // 256 = b(4) qt(64)
  int qt = bx & 63, b = bx >> 6;
  __shared__ short Kl[64][136];
  __shared__ short Vl[128][72];
  __shared__ short Pl[4][16 * 72];
  int t = threadIdx.x;
  int lane = t & 63, w = t >> 6, l15 = lane & 15, quad = lane >> 4;

  s8b aq[4];
  {
    const short* qp = q + ((size_t)(b * NSP + qt * 64 + w * 16 + l15)) * CCH + quad * 8;
    #pragma unroll
    for (int kc = 0; kc < 4; ++kc) aq[kc] = *(const s8b*)(qp + kc * 32);
  }
  f32x4 O[8];
  #pragma unroll
  for (int cg = 0; cg < 8; ++cg) O[cg] = (f32x4){0.f, 0.f, 0.f, 0.f};
  float m[4] = {-1e30f, -1e30f, -1e30f, -1e30f};
  float l[4] = {0.f, 0.f, 0.f, 0.f};

  for (int kt = 0; kt < 64; ++kt) {
    __syncthreads();
    for (int idx = t; idx < 64 * 16; idx += 256) {
      int row = idx >> 4, c8 = idx & 15;
      *(s8b*)&Kl[row][c8 * 8] =
          *(const s8b*)(k + ((size_t)(b * NSP + kt * 64 + row)) * CCH + c8 * 8);
    }
    for (int idx = t; idx < 128 * 8; idx += 256) {
      int row = idx >> 3, k8 = idx & 7;
      *(s8b*)&Vl[row][k8 * 8] =
          *(const s8b*)(vt + ((size_t)(b * CCH + row)) * NSP + kt * 64 + k8 * 8);
    }
    __syncthreads();

    // S = Q K^T (16 q-rows x 64 keys per wave)
    f32x4 s[4];
    #pragma unroll
    for (int g = 0; g < 4; ++g) {
      f32x4 acc = {0.f, 0.f, 0.f, 0.f};
      #pragma unroll
      for (int kc = 0; kc < 4; ++kc) {
        s8b bk = *(const s8b*)&Kl[g * 16 + l15][kc * 32 + quad * 8];
        acc = mfma16(aq[kc], bk, acc);
      }
      s[g] = acc;
    }
    // online softmax (fp32)
    #pragma unroll
    for (int g = 0; g < 4; ++g)
      #pragma unroll
      for (int r = 0; r < 4; ++r) s[g][r] *= ATT_SCALE;
    float mx[4];
    #pragma unroll
    for (int r = 0; r < 4; ++r)
      mx[r] = fmaxf(fmaxf(s[0][r], s[1][r]), fmaxf(s[2][r], s[3][r]));
    #pragma unroll
    for (int off = 1; off < 16; off <<= 1)
      #pragma unroll
      for (int r = 0; r < 4; ++r) mx[r] = fmaxf(mx[r], __shfl_xor(mx[r], off));
    float al[4];
    #pragma unroll
    for (int r = 0; r < 4; ++r) {
      float mn = fmaxf(m[r], mx[r]);
      al[r] = __expf(m[r] - mn);
      m[r] = mn;
    }
    #pragma unroll
    for (int g = 0; g < 4; ++g)
      #pragma unroll
      for (int r = 0; r < 4; ++r) s[g][r] = __expf(s[g][r] - m[r]);
    float rs[4];
    #pragma unroll
    for (int r = 0; r < 4; ++r) rs[r] = (s[0][r] + s[1][r]) + (s[2][r] + s[3][r]);
    #pragma unroll
    for (int off = 1; off < 16; off <<= 1)
      #pragma unroll
      for (int r = 0; r < 4; ++r) rs[r] += __shfl_xor(rs[r], off);
    #pragma unroll
    for (int r = 0; r < 4; ++r) l[r] = l[r] * al[r] + rs[r];
    #pragma unroll
    for (int cg = 0; cg < 8; ++cg)
      #pragma unroll
      for (int r = 0; r < 4; ++r) O[cg][r] *= al[r];

    // P: C-layout -> LDS -> A-layout (per-wave region, no barrier needed)
    short* pw = &Pl[w][0];
    #pragma unroll
    for (int g = 0; g < 4; ++g)
      #pragma unroll
      for (int r = 0; r < 4; ++r)
        pw[(quad * 4 + r) * 72 + g * 16 + l15] = f2bf(s[g][r]);
    s8b pf[2];
    #pragma unroll
    for (int kk = 0; kk < 2; ++kk)
      pf[kk] = *(const s8b*)&Pl[w][l15 * 72 + kk * 32 + quad * 8];
    // O += P V
    #pragma unroll
    for (int cg = 0; cg < 8; ++cg) {
      #pragma unroll
      for (int kk = 0; kk < 2; ++kk) {
        s8b vf = *(const s8b*)&Vl[cg * 16 + l15][kk * 32 + quad * 8];
        O[cg] = mfma16(pf[kk], vf, O[cg]);
      }
    }
  }
  float linv[4];
  #pragma unroll
  for (int r = 0; r < 4; ++r) linv[r] = 1.f / l[r];
  #pragma unroll
  for (int cg = 0; cg < 8; ++cg)
    #pragma unroll
    for (int r = 0; r < 4; ++r) {
      int n = qt * 64 + w * 16 + quad * 4 + r;
      ao[((size_t)(b * NSP + n)) * CCH + cg * 16 + l15] = f2bf(O[cg][r] * linv[r]);
    }
}

// ---------------- proj + bias + residual: out (b,c,n) fp32 ----------------
__global__ void proj_gemm(const short* __restrict__ ao, const float* __restrict__ Wp,
                          const float* __restrict__ pbias, const float* __restrict__ x,
                          float* __restrict__ out) {
  int bx = blockIdx.x;            // 256 = b(4) nt(64)
  int nt = bx & 63, b = bx >> 6;
  __shared__ short Wl[128][136];
  int t = threadIdx.x;
  for (int idx = t; idx < 128 * 16; idx += 256) {
    int row = idx >> 4, c8 = idx & 15;
    const float* src = Wp + (size_t)row * CCH + c8 * 8;
    s8b wv;
    #pragma unroll
    for (int j = 0; j < 8; ++j) wv[j] = f2bf(src[j]);
    *(s8b*)&Wl[row][c8 * 8] = wv;
  }
  __syncthreads();
  int lane = t & 63, w = t >> 6, l15 = lane & 15, quad = lane >> 4;
  s8b bfr[4];
  const short* ap = ao + ((size_t)(b * NSP + nt * 64 + w * 16 + l15)) * CCH + quad * 8;
  #pragma unroll
  for (int kc = 0; kc < 4; ++kc) bfr[kc] = *(const s8b*)(ap + kc * 32);
  #pragma unroll
  for (int cg = 0; cg < 8; ++cg) {
    f32x4 acc = {0.f, 0.f, 0.f, 0.f};
    #pragma unroll
    for (int kc = 0; kc < 4; ++kc) {
      s8b aw = *(const s8b*)&Wl[cg * 16 + l15][kc * 32 + quad * 8];
      acc = mfma16(aw, bfr[kc], acc);
    }
    #pragma unroll
    for (int r = 0; r < 4; ++r) {
      int co = cg * 16 + quad * 4 + r;
      int n = nt * 64 + w * 16 + l15;
      size_t off = ((size_t)(b * CCH + co)) * NSP + n;
      out[off] = x[off] + acc[r] + pbias[co];
    }
  }
}

extern "C" void kernel_launch(void* const* d_in, const int* in_sizes, int n_in,
                              void* d_out, int out_size, void* d_ws, size_t ws_size,
                              hipStream_t stream) {
  (void)in_sizes; (void)n_in; (void)out_size; (void)ws_size;
  const float* x    = (const float*)d_in[0];
  const float* gw   = (const float*)d_in[1];
  const float* gb   = (const float*)d_in[2];
  const float* Wqkv = (const float*)d_in[3];
  const float* bqkv = (const float*)d_in[4];
  const float* Wp   = (const float*)d_in[5];
  const float* bp   = (const float*)d_in[6];
  float* out = (float*)d_out;
  char* ws = (char*)d_ws;
  float* stats = (float*)ws;
  short* xn = (short*)(ws + 256);
  short* q  = (short*)(ws + 256 + 1ull * 4194304);
  short* k  = (short*)(ws + 256 + 2ull * 4194304);
  short* vt = (short*)(ws + 256 + 3ull * 4194304);
  short* ao = (short*)(ws + 256 + 4ull * 4194304);

  hipMemsetAsync(stats, 0, 64 * sizeof(float), stream);
  gn_stats<<<256, 256, 0, stream>>>(x, stats);
  gn_apply<<<256, 256, 0, stream>>>(x, gw, gb, stats, xn);
  qk_gemm<<<1024, 256, 0, stream>>>(xn, Wqkv, bqkv, q, k);
  v_gemm<<<256, 256, 0, stream>>>(xn, Wqkv, bqkv, vt);
  flash<<<256, 256, 0, stream>>>(q, k, vt, ao);
  proj_gemm<<<256, 256, 0, stream>>>(ao, Wp, bp, x, out);
}

// Round 2
// 221.118 us; speedup vs baseline: 1.5998x; 1.5998x over previous
//
#include <hip/hip_runtime.h>

#define BATCH 4
#define CCH 128
#define NSP 4096
#define NGRP 8
#define GROUP_ELEMS 65536   // 16 ch * 4096
#define ATT_SCALE 0.08838834764831845f
#define EPS_GN 1e-5f

typedef short s8b __attribute__((ext_vector_type(8)));
typedef float f32x4 __attribute__((ext_vector_type(4)));

static __device__ __forceinline__ short f2bf(float f) {
  union { float f; unsigned u; } v; v.f = f;
  unsigned r = (v.u + 0x7FFFu + ((v.u >> 16) & 1u)) >> 16;
  return (short)r;
}

static __device__ __forceinline__ f32x4 mfma16(s8b a, s8b b, f32x4 c) {
  return __builtin_amdgcn_mfma_f32_16x16x32_bf16(a, b, c, 0, 0, 0);
}

// ---------------- GroupNorm pass 1: per-(b,g) sum / sumsq ----------------
__global__ void gn_stats(const float* __restrict__ x, float* __restrict__ stats) {
  int bx = blockIdx.x;            // 256 = bg(32) * chunk(8)
  int ch = bx & 7, bg = bx >> 3;
  const float* base = x + (size_t)bg * GROUP_ELEMS + (size_t)ch * 8192;
  int t = threadIdx.x;
  float s = 0.f, ss = 0.f;
  #pragma unroll
  for (int i = 0; i < 8; ++i) {
    float4 v = *(const float4*)(base + i * 1024 + t * 4);
    s  += v.x + v.y + v.z + v.w;
    ss += v.x * v.x + v.y * v.y + v.z * v.z + v.w * v.w;
  }
  #pragma unroll
  for (int off = 1; off < 64; off <<= 1) {
    s  += __shfl_xor(s, off);
    ss += __shfl_xor(ss, off);
  }
  __shared__ float red[8];
  int w = t >> 6;
  if ((t & 63) == 0) { red[w * 2] = s; red[w * 2 + 1] = ss; }
  __syncthreads();
  if (t == 0) {
    atomicAdd(&stats[bg * 2],     red[0] + red[2] + red[4] + red[6]);
    atomicAdd(&stats[bg * 2 + 1], red[1] + red[3] + red[5] + red[7]);
  }
}

// ---------------- GroupNorm pass 2: normalize, write xn as (b,n,c) bf16 ----------------
__global__ void gn_apply(const float* __restrict__ x, const float* __restrict__ gw,
                         const float* __restrict__ gb, const float* __restrict__ stats,
                         short* __restrict__ xn) {
  int bx = blockIdx.x;            // 256 = b(4) g(8) ns(8)
  int ns = bx & 7, g = (bx >> 3) & 7, b = bx >> 6;
  int bg = b * NGRP + g;
  float mean = stats[bg * 2] * (1.f / GROUP_ELEMS);
  float var  = stats[bg * 2 + 1] * (1.f / GROUP_ELEMS) - mean * mean;
  float inv  = rsqrtf(var + EPS_GN);
  int t = threadIdx.x;
  int cl = t & 15, n4 = t >> 4;
  int c = g * 16 + cl;
  float ga = gw[c] * inv;
  float be = gb[c] - mean * ga;
  const float* xr = x + (size_t)(b * CCH + c) * NSP;
  short* xo = xn + (size_t)b * NSP * CCH + c;
  #pragma unroll
  for (int i = 0; i < 8; ++i) {
    int n = ns * 512 + i * 64 + n4 * 4;
    float4 v = *(const float4*)(xr + n);
    xo[(size_t)(n + 0) * CCH] = f2bf(v.x * ga + be);
    xo[(size_t)(n + 1) * CCH] = f2bf(v.y * ga + be);
    xo[(size_t)(n + 2) * CCH] = f2bf(v.z * ga + be);
    xo[(size_t)(n + 3) * CCH] = f2bf(v.w * ga + be);
  }
}

// ---------------- QKV (q,k part): D[n][o], writes q,k as (b,n,c) bf16 ----------------
__global__ void qk_gemm(const short* __restrict__ xn, const float* __restrict__ Wqkv,
                        const float* __restrict__ bias, short* __restrict__ q,
                        short* __restrict__ k) {
  int bx = blockIdx.x;            // 1024 = b(4) nt(64) ot(4)
  int ot = bx & 3, nt = (bx >> 2) & 63, b = bx >> 8;
  __shared__ short Xl[64][136];
  __shared__ short Wl[64][136];
  int t = threadIdx.x;
  for (int idx = t; idx < 64 * 16; idx += 256) {
    int row = idx >> 4, c8 = idx & 15;
    *(s8b*)&Xl[row][c8 * 8] =
        *(const s8b*)(xn + ((size_t)(b * NSP + nt * 64 + row)) * CCH + c8 * 8);
  }
  for (int idx = t; idx < 64 * 16; idx += 256) {
    int row = idx >> 4, c8 = idx & 15;
    const float* src = Wqkv + (size_t)(ot * 64 + row) * CCH + c8 * 8;
    s8b wv;
    #pragma unroll
    for (int j = 0; j < 8; ++j) wv[j] = f2bf(src[j]);
    *(s8b*)&Wl[row][c8 * 8] = wv;
  }
  __syncthreads();
  int lane = t & 63, w = t >> 6, l15 = lane & 15, quad = lane >> 4;
  s8b a[4];
  #pragma unroll
  for (int kc = 0; kc < 4; ++kc) a[kc] = *(const s8b*)&Xl[w * 16 + l15][kc * 32 + quad * 8];
  #pragma unroll
  for (int o4 = 0; o4 < 4; ++o4) {
    f32x4 acc = {0.f, 0.f, 0.f, 0.f};
    #pragma unroll
    for (int kc = 0; kc < 4; ++kc) {
      s8b bw = *(const s8b*)&Wl[o4 * 16 + l15][kc * 32 + quad * 8];
      acc = mfma16(a[kc], bw, acc);
    }
    int obase = ot * 64 + o4 * 16;
    short* dst = (obase < 128) ? q : k;
    int oc = obase - ((obase < 128) ? 0 : 128) + l15;
    float bs = bias[obase + l15];
    #pragma unroll
    for (int r = 0; r < 4; ++r) {
      int n = nt * 64 + w * 16 + quad * 4 + r;
      dst[((size_t)(b * NSP + n)) * CCH + oc] = f2bf(acc[r] + bs);
    }
  }
}

// ---------------- QKV (v part): D[o][n], writes v transposed (b,c,n) bf16 ----------------
__global__ void v_gemm(const short* __restrict__ xn, const float* __restrict__ Wqkv,
                       const float* __restrict__ bias, short* __restrict__ vt) {
  int bx = blockIdx.x;            // 256 = b(4) nt(32) ot(2)
  int ot = bx & 1, nt = (bx >> 1) & 31, b = bx >> 6;
  __shared__ short Xl[128][136];
  __shared__ short Wl[64][136];
  int t = threadIdx.x;
  for (int idx = t; idx < 128 * 16; idx += 256) {
    int row = idx >> 4, c8 = idx & 15;
    *(s8b*)&Xl[row][c8 * 8] =
        *(const s8b*)(xn + ((size_t)(b * NSP + nt * 128 + row)) * CCH + c8 * 8);
  }
  for (int idx = t; idx < 64 * 16; idx += 256) {
    int row = idx >> 4, c8 = idx & 15;
    const float* src = Wqkv + (size_t)(256 + ot * 64 + row) * CCH + c8 * 8;
    s8b wv;
    #pragma unroll
    for (int j = 0; j < 8; ++j) wv[j] = f2bf(src[j]);
    *(s8b*)&Wl[row][c8 * 8] = wv;
  }
  __syncthreads();
  int lane = t & 63, w = t >> 6, l15 = lane & 15, quad = lane >> 4;
  s8b a[4];
  #pragma unroll
  for (int kc = 0; kc < 4; ++kc) a[kc] = *(const s8b*)&Wl[w * 16 + l15][kc * 32 + quad * 8];
  float bs[4];
  #pragma unroll
  for (int r = 0; r < 4; ++r) bs[r] = bias[256 + ot * 64 + w * 16 + quad * 4 + r];
  #pragma unroll
  for (int ntile = 0; ntile < 8; ++ntile) {
    f32x4 acc = {0.f, 0.f, 0.f, 0.f};
    #pragma unroll
    for (int kc = 0; kc < 4; ++kc) {
      s8b bx2 = *(const s8b*)&Xl[ntile * 16 + l15][kc * 32 + quad * 8];
      acc = mfma16(a[kc], bx2, acc);
    }
    #pragma unroll
    for (int r = 0; r < 4; ++r) {
      int og = ot * 64 + w * 16 + quad * 4 + r;       // v channel
      int n = nt * 128 + ntile * 16 + l15;
      vt[((size_t)(b * CCH + og)) * NSP + n] = f2bf(acc[r] + bs[r]);
    }
  }
}

// ---------------- Flash attention v2 ----------------
// 512 thr = 8 waves = 4 KV-split groups x 2 waves; wave owns 32 q-rows (2 m-tiles).
// K/V B-fragments loaded DIRECTLY from global (no staging LDS, no loop barriers).
// Group g sweeps kt = g + 4*i (i=0..15); partials merged via LDS at the end.
__global__ __launch_bounds__(512) void flash(const short* __restrict__ q,
                                             const short* __restrict__ k,
                                             const short* __restrict__ vt,
                                             short* __restrict__ ao) {
  int bx = blockIdx.x;            // 256 = b(4) qt(64)
  int qt = bx & 63, b = bx >> 6;
  __shared__ float Obuf[64 * 132];            // 33792 B, pitch 132 breaks bank alignment
  __shared__ float Mbuf[64];
  __shared__ float Lbuf[64];
  __shared__ short Pl[8][32 * 72];            // per-wave P transpose, 36864 B
  int t = threadIdx.x;
  int lane = t & 63, w = t >> 6;              // w in [0,8)
  int g = w >> 1, wg = w & 1;                 // kv group / q sub-tile
  int l15 = lane & 15, quad = lane >> 4;

  // Q A-fragments, resident (rows qt*64 + wg*32 + mt*16 + l15)
  s8b aq[2][4];
  #pragma unroll
  for (int mt = 0; mt < 2; ++mt) {
    const short* qp =
        q + ((size_t)(b * NSP + qt * 64 + wg * 32 + mt * 16 + l15)) * CCH + quad * 8;
    #pragma unroll
    for (int kc = 0; kc < 4; ++kc) aq[mt][kc] = *(const s8b*)(qp + kc * 32);
  }
  f32x4 O[2][8];
  float m[2][4], l[2][4];
  #pragma unroll
  for (int mt = 0; mt < 2; ++mt) {
    #pragma unroll
    for (int cg = 0; cg < 8; ++cg) O[mt][cg] = (f32x4){0.f, 0.f, 0.f, 0.f};
    #pragma unroll
    for (int r = 0; r < 4; ++r) { m[mt][r] = -1e30f; l[mt][r] = 0.f; }
  }
  const short* kbase = k + (size_t)b * NSP * CCH;
  const short* vbase = vt + (size_t)b * CCH * NSP;
  short* pw = &Pl[w][0];

  for (int i = 0; i < 16; ++i) {
    int ktv = (g + 4 * i) * 64;               // this group's 64-key tile base
    // ---- S = Q K^T : 32 q-rows x 64 keys ----
    f32x4 s[2][4];
    #pragma unroll
    for (int mt = 0; mt < 2; ++mt)
      #pragma unroll
      for (int g2 = 0; g2 < 4; ++g2) s[mt][g2] = (f32x4){0.f, 0.f, 0.f, 0.f};
    #pragma unroll
    for (int g2 = 0; g2 < 4; ++g2) {
      const short* kp = kbase + (size_t)(ktv + g2 * 16 + l15) * CCH + quad * 8;
      s8b bk[4];
      #pragma unroll
      for (int kc = 0; kc < 4; ++kc) bk[kc] = *(const s8b*)(kp + kc * 32);
      #pragma unroll
      for (int mt = 0; mt < 2; ++mt)
        #pragma unroll
        for (int kc = 0; kc < 4; ++kc) s[mt][g2] = mfma16(aq[mt][kc], bk[kc], s[mt][g2]);
    }
    // ---- V fragments (independent of softmax; issue early) ----
    s8b vf[8][2];
    #pragma unroll
    for (int cg = 0; cg < 8; ++cg) {
      const short* vp = vbase + (size_t)(cg * 16 + l15) * NSP + ktv + quad * 8;
      vf[cg][0] = *(const s8b*)(vp);
      vf[cg][1] = *(const s8b*)(vp + 32);
    }
    // ---- online softmax (per m-tile, rows owned by quad) ----
    #pragma unroll
    for (int mt = 0; mt < 2; ++mt) {
      #pragma unroll
      for (int g2 = 0; g2 < 4; ++g2)
        #pragma unroll
        for (int r = 0; r < 4; ++r) s[mt][g2][r] *= ATT_SCALE;
      float mx[4];
      #pragma unroll
      for (int r = 0; r < 4; ++r)
        mx[r] = fmaxf(fmaxf(s[mt][0][r], s[mt][1][r]), fmaxf(s[mt][2][r], s[mt][3][r]));
      #pragma unroll
      for (int off = 1; off < 16; off <<= 1)
        #pragma unroll
        for (int r = 0; r < 4; ++r) mx[r] = fmaxf(mx[r], __shfl_xor(mx[r], off));
      float al[4];
      #pragma unroll
      for (int r = 0; r < 4; ++r) {
        float mn = fmaxf(m[mt][r], mx[r]);
        al[r] = __expf(m[mt][r] - mn);
        m[mt][r] = mn;
      }
      #pragma unroll
      for (int g2 = 0; g2 < 4; ++g2)
        #pragma unroll
        for (int r = 0; r < 4; ++r) s[mt][g2][r] = __expf(s[mt][g2][r] - m[mt][r]);
      float rs[4];
      #pragma unroll
      for (int r = 0; r < 4; ++r)
        rs[r] = (s[mt][0][r] + s[mt][1][r]) + (s[mt][2][r] + s[mt][3][r]);
      #pragma unroll
      for (int off = 1; off < 16; off <<= 1)
        #pragma unroll
        for (int r = 0; r < 4; ++r) rs[r] += __shfl_xor(rs[r], off);
      #pragma unroll
      for (int r = 0; r < 4; ++r) l[mt][r] = l[mt][r] * al[r] + rs[r];
      #pragma unroll
      for (int cg = 0; cg < 8; ++cg)
        #pragma unroll
        for (int r = 0; r < 4; ++r) O[mt][cg][r] *= al[r];
      // P: C-layout -> per-wave LDS
      #pragma unroll
      for (int g2 = 0; g2 < 4; ++g2)
        #pragma unroll
        for (int r = 0; r < 4; ++r)
          pw[(mt * 16 + quad * 4 + r) * 72 + g2 * 16 + l15] = f2bf(s[mt][g2][r]);
    }
    // ---- P A-fragments ----
    s8b pf[2][2];
    #pragma unroll
    for (int mt = 0; mt < 2; ++mt)
      #pragma unroll
      for (int kk = 0; kk < 2; ++kk)
        pf[mt][kk] = *(const s8b*)&pw[(mt * 16 + l15) * 72 + kk * 32 + quad * 8];
    // ---- O += P V ----
    #pragma unroll
    for (int cg = 0; cg < 8; ++cg) {
      #pragma unroll
      for (int mt = 0; mt < 2; ++mt) {
        O[mt][cg] = mfma16(pf[mt][0], vf[cg][0], O[mt][cg]);
        O[mt][cg] = mfma16(pf[mt][1], vf[cg][1], O[mt][cg]);
      }
    }
  }

  // ---- merge the 4 KV-groups through LDS (4 uniform barrier phases) ----
  for (int ph = 0; ph < 4; ++ph) {
    if (g == ph) {
      if (ph == 0) {
        #pragma unroll
        for (int mt = 0; mt < 2; ++mt)
          #pragma unroll
          for (int r = 0; r < 4; ++r) {
            int row = wg * 32 + mt * 16 + quad * 4 + r;
            if (l15 == 0) { Mbuf[row] = m[mt][r]; Lbuf[row] = l[mt][r]; }
            #pragma unroll
            for (int cg = 0; cg < 8; ++cg)
              Obuf[row * 132 + cg * 16 + l15] = O[mt][cg][r];
          }
      } else {
        #pragma unroll
        for (int mt = 0; mt < 2; ++mt)
          #pragma unroll
          for (int r = 0; r < 4; ++r) {
            int row = wg * 32 + mt * 16 + quad * 4 + r;
            float Mb = Mbuf[row];
            float mn = fmaxf(Mb, m[mt][r]);
            float a0 = __expf(Mb - mn), a1 = __expf(m[mt][r] - mn);
            #pragma unroll
            for (int cg = 0; cg < 8; ++cg) {
              float o = Obuf[row * 132 + cg * 16 + l15];
              Obuf[row * 132 + cg * 16 + l15] = o * a0 + O[mt][cg][r] * a1;
            }
            if (l15 == 0) {
              Lbuf[row] = Lbuf[row] * a0 + l[mt][r] * a1;
              Mbuf[row] = mn;
            }
          }
      }
    }
    __syncthreads();
  }
  // ---- normalize + write ao (coalesced: 8 threads per row) ----
  {
    int row = t >> 3, c0 = (t & 7) * 16;
    float linv = 1.f / Lbuf[row];
    short* dst = ao + ((size_t)(b * NSP + qt * 64 + row)) * CCH + c0;
    #pragma unroll
    for (int ii = 0; ii < 4; ++ii) {
      float4 ov = *(const float4*)&Obuf[row * 132 + c0 + ii * 4];
      dst[ii * 4 + 0] = f2bf(ov.x * linv);
      dst[ii * 4 + 1] = f2bf(ov.y * linv);
      dst[ii * 4 + 2] = f2bf(ov.z * linv);
      dst[ii * 4 + 3] = f2bf(ov.w * linv);
    }
  }
}

// ---------------- proj + bias + residual: out (b,c,n) fp32 ----------------
__global__ void proj_gemm(const short* __restrict__ ao, const float* __restrict__ Wp,
                          const float* __restrict__ pbias, const float* __restrict__ x,
                          float* __restrict__ out) {
  int bx = blockIdx.x;            // 256 = b(4) nt(64)
  int nt = bx & 63, b = bx >> 6;
  __shared__ short Wl[128][136];
  int t = threadIdx.x;
  for (int idx = t; idx < 128 * 16; idx += 256) {
    int row = idx >> 4, c8 = idx & 15;
    const float* src = Wp + (size_t)row * CCH + c8 * 8;
    s8b wv;
    #pragma unroll
    for (int j = 0; j < 8; ++j) wv[j] = f2bf(src[j]);
    *(s8b*)&Wl[row][c8 * 8] = wv;
  }
  __syncthreads();
  int lane = t & 63, w = t >> 6, l15 = lane & 15, quad = lane >> 4;
  s8b bfr[4];
  const short* ap = ao + ((size_t)(b * NSP + nt * 64 + w * 16 + l15)) * CCH + quad * 8;
  #pragma unroll
  for (int kc = 0; kc < 4; ++kc) bfr[kc] = *(const s8b*)(ap + kc * 32);
  #pragma unroll
  for (int cg = 0; cg < 8; ++cg) {
    f32x4 acc = {0.f, 0.f, 0.f, 0.f};
    #pragma unroll
    for (int kc = 0; kc < 4; ++kc) {
      s8b aw = *(const s8b*)&Wl[cg * 16 + l15][kc * 32 + quad * 8];
      acc = mfma16(aw, bfr[kc], acc);
    }
    #pragma unroll
    for (int r = 0; r < 4; ++r) {
      int co = cg * 16 + quad * 4 + r;
      int n = nt * 64 + w * 16 + l15;
      size_t off = ((size_t)(b * CCH + co)) * NSP + n;
      out[off] = x[off] + acc[r] + pbias[co];
    }
  }
}

extern "C" void kernel_launch(void* const* d_in, const int* in_sizes, int n_in,
                              void* d_out, int out_size, void* d_ws, size_t ws_size,
                              hipStream_t stream) {
  (void)in_sizes; (void)n_in; (void)out_size; (void)ws_size;
  const float* x    = (const float*)d_in[0];
  const float* gw   = (const float*)d_in[1];
  const float* gb   = (const float*)d_in[2];
  const float* Wqkv = (const float*)d_in[3];
  const float* bqkv = (const float*)d_in[4];
  const float* Wp   = (const float*)d_in[5];
  const float* bp   = (const float*)d_in[6];
  float* out = (float*)d_out;
  char* ws = (char*)d_ws;
  float* stats = (float*)ws;
  short* xn = (short*)(ws + 256);
  short* q  = (short*)(ws + 256 + 1ull * 4194304);
  short* k  = (short*)(ws + 256 + 2ull * 4194304);
  short* vt = (short*)(ws + 256 + 3ull * 4194304);
  short* ao = (short*)(ws + 256 + 4ull * 4194304);

  hipMemsetAsync(stats, 0, 64 * sizeof(float), stream);
  gn_stats<<<256, 256, 0, stream>>>(x, stats);
  gn_apply<<<256, 256, 0, stream>>>(x, gw, gb, stats, xn);
  qk_gemm<<<1024, 256, 0, stream>>>(xn, Wqkv, bqkv, q, k);
  v_gemm<<<256, 256, 0, stream>>>(xn, Wqkv, bqkv, vt);
  flash<<<256, 512, 0, stream>>>(q, k, vt, ao);
  proj_gemm<<<256, 256, 0, stream>>>(ao, Wp, bp, x, out);
}